// Round 2
// baseline (1325.353 us; speedup 1.0000x reference)
//
#include <hip/hip_runtime.h>

typedef unsigned short u16;
typedef __attribute__((ext_vector_type(8))) short bf16x8;
typedef __attribute__((ext_vector_type(4))) float f32x4;

#define NH 32
#define NKV 8
#define HD 128
#define SEQ 2048
#define DMODEL 4096
#define QKVN 6144
#define RMS_EPS 1e-6f
#define SM_SCALE 0.08838834764831845f

__device__ __forceinline__ u16 f2bf(float f) {
  unsigned int u = __float_as_uint(f);
  u += 0x7FFFu + ((u >> 16) & 1u);
  return (u16)(u >> 16);
}
__device__ __forceinline__ float bf2f(u16 b) {
  return __uint_as_float(((unsigned int)b) << 16);
}

__device__ __forceinline__ f32x4 mfma16(bf16x8 a, bf16x8 b, f32x4 c) {
  return __builtin_amdgcn_mfma_f32_16x16x32_bf16(a, b, c, 0, 0, 0);
}

__device__ __forceinline__ void stage16(const u16* g, u16* l) {
  __builtin_amdgcn_global_load_lds(
      (const __attribute__((address_space(1))) unsigned int*)g,
      (__attribute__((address_space(3))) unsigned int*)l, 16, 0, 0);
}

// ---------------- convert x: f32 -> bf16 ----------------
__global__ __launch_bounds__(256) void cvt_f32_bf16(const float* __restrict__ in,
                                                    u16* __restrict__ out, int n4) {
  int stride = gridDim.x * blockDim.x;
  for (int i = blockIdx.x * blockDim.x + threadIdx.x; i < n4; i += stride) {
    float4 v = ((const float4*)in)[i];
    ushort4 o;
    o.x = f2bf(v.x); o.y = f2bf(v.y); o.z = f2bf(v.z); o.w = f2bf(v.w);
    ((ushort4*)out)[i] = o;
  }
}

// ---------------- transpose-convert W[K=4096][N] f32 -> Wt[rowoff+N][4096] bf16 ----------------
__global__ __launch_bounds__(256) void tconv(const float* __restrict__ W, u16* __restrict__ Wt,
                                             int N, int rowoff) {
  __shared__ float t[32][33];
  int n0 = blockIdx.x * 32, k0 = blockIdx.y * 32;
  int tx = threadIdx.x, ty = threadIdx.y;  // (32,8)
#pragma unroll
  for (int i = 0; i < 4; ++i)
    t[ty + i * 8][tx] = W[(size_t)(k0 + ty + i * 8) * N + n0 + tx];
  __syncthreads();
#pragma unroll
  for (int i = 0; i < 4; ++i)
    Wt[(size_t)(rowoff + n0 + ty + i * 8) * DMODEL + k0 + tx] = f2bf(t[tx][ty + i * 8]);
}

// ---------------- GEMM: C[M][N] = A[M][K] * Bt[N][K]^T (bf16, m97 structure) ----------------
__device__ __forceinline__ void storeC(u16* p, float v) { *p = f2bf(v); }
__device__ __forceinline__ void storeC(float* p, float v) { *p = v; }

template <typename OutT>
__global__ __launch_bounds__(256) void gemm_bt(const u16* __restrict__ A, const u16* __restrict__ Bt,
                                               OutT* __restrict__ C, int M, int N, int K) {
  __shared__ __align__(16) u16 As[128 * 32];
  __shared__ __align__(16) u16 Bs[128 * 32];
  int m0 = blockIdx.x * 128, n0 = blockIdx.y * 128;
  int tid = threadIdx.x, wave = tid >> 6, lane = tid & 63;
  int wm = (wave >> 1) * 64, wn = (wave & 1) * 64;
  f32x4 acc[4][4] = {};
  int srow = lane >> 2;         // 16 rows per 1KB chunk, 4 lanes/row
  int scol = (lane & 3) * 8;    // 8 bf16 = 16B per lane
  int fr = lane & 15, fq = lane >> 4;

  for (int kb = 0; kb < K; kb += 32) {
    __syncthreads();
#pragma unroll
    for (int c = 0; c < 2; ++c) {
      int chunk = wave * 2 + c;  // 0..7
      int row = chunk * 16 + srow;
      stage16(A + (size_t)(m0 + row) * K + kb + scol, As + chunk * 512);
      stage16(Bt + (size_t)(n0 + row) * K + kb + scol, Bs + chunk * 512);
    }
    __syncthreads();
    bf16x8 af[4], bfv[4];
#pragma unroll
    for (int i = 0; i < 4; ++i) af[i] = *(const bf16x8*)&As[(wm + i * 16 + fr) * 32 + fq * 8];
#pragma unroll
    for (int j = 0; j < 4; ++j) bfv[j] = *(const bf16x8*)&Bs[(wn + j * 16 + fr) * 32 + fq * 8];
#pragma unroll
    for (int i = 0; i < 4; ++i)
#pragma unroll
      for (int j = 0; j < 4; ++j)
        acc[i][j] = mfma16(af[i], bfv[j], acc[i][j]);
  }
#pragma unroll
  for (int i = 0; i < 4; ++i)
#pragma unroll
    for (int j = 0; j < 4; ++j)
#pragma unroll
      for (int r = 0; r < 4; ++r) {
        int row = m0 + wm + i * 16 + fq * 4 + r;
        int col = n0 + wn + j * 16 + fr;
        storeC(&C[(size_t)row * N + col], acc[i][j][r]);
      }
}

// ---------------- RMSNorm + RoPE in place on Q/K slices of QKV ----------------
__global__ __launch_bounds__(256) void normrope(u16* __restrict__ QKV,
                                                const float* __restrict__ qw,
                                                const float* __restrict__ kw) {
  int wq = threadIdx.x >> 6, lane = threadIdx.x & 63;
  int gid = blockIdx.x * 4 + wq;
  int token = gid / 40, head = gid % 40;
  int pos = token & (SEQ - 1);
  const float* wrow;
  int col;
  if (head < NH) { wrow = qw; col = head * HD; }
  else           { wrow = kw; col = DMODEL + (head - NH) * HD; }
  u16* row = QKV + (size_t)token * QKVN + col;
  ushort2 xv = *(const ushort2*)(row + 2 * lane);
  float x1 = bf2f(xv.x), x2 = bf2f(xv.y);
  float ssq = x1 * x1 + x2 * x2;
#pragma unroll
  for (int o = 32; o; o >>= 1) ssq += __shfl_xor(ssq, o, 64);
  float rms = rsqrtf(ssq * (1.0f / HD) + RMS_EPS);
  float y1 = x1 * rms * wrow[2 * lane];
  float y2 = x2 * rms * wrow[2 * lane + 1];
  // freq = 10000^(-lane/64) = 2^(-lane * log2(10000)/64)
  float freq = exp2f((float)lane * -0.20762050593046014f);
  float ang = (float)pos * freq;
  float s, c;
  sincosf(ang, &s, &c);
  ushort2 ov;
  ov.x = f2bf(y1 * c - y2 * s);
  ov.y = f2bf(y1 * s + y2 * c);
  *(ushort2*)(row + 2 * lane) = ov;
}

// ---------------- causal GQA flash attention ----------------
__global__ __launch_bounds__(256) void attn(const u16* __restrict__ QKV, u16* __restrict__ O) {
  int bid = blockIdx.x;
  int qt = bid & 31, h = (bid >> 5) & 31, b = bid >> 10;
  int qbase = qt * 64;
  int tid = threadIdx.x, wq = tid >> 6, lane = tid & 63;
  int q0 = qbase + wq * 16;
  int kvh = h >> 2;

  __shared__ __align__(16) u16 Ks[32 * 128];       // swizzled [kv][d]
  __shared__ __align__(16) u16 Vs[128 * 40];       // [d][kv], kv padded 32->40
  __shared__ __align__(16) u16 Ps[4][16 * 40];     // per-wave P [q][kv], pad 40

  size_t tokbase = (size_t)b * SEQ;
  int fr = lane & 15, fq = lane >> 4;

  bf16x8 qf[4];
  {
    const u16* qrow = QKV + (tokbase + q0 + fr) * QKVN + h * HD;
#pragma unroll
    for (int c = 0; c < 4; ++c)
      qf[c] = *(const bf16x8*)(qrow + c * 32 + fq * 8);
  }
  f32x4 outp[8] = {};
  float mrow[4] = {-1e30f, -1e30f, -1e30f, -1e30f};
  float lrow[4] = {0.f, 0.f, 0.f, 0.f};

  const u16* Kbase = QKV + tokbase * QKVN + DMODEL + kvh * HD;
  const u16* Vbase = QKV + tokbase * QKVN + DMODEL + NKV * HD + kvh * HD;

  int kvend = qbase + 64;
  for (int kv0 = 0; kv0 < kvend; kv0 += 32) {
    __syncthreads();
    // stage K (swizzled) and V (transposed) : 32 rows x 128 d each
#pragma unroll
    for (int i = 0; i < 2; ++i) {
      int idx = i * 256 + tid;
      int row = idx >> 4, sl = idx & 15;
      bf16x8 dk = *(const bf16x8*)(Kbase + (size_t)(kv0 + row) * QKVN + sl * 8);
      *(bf16x8*)((char*)Ks + row * 256 + ((sl * 16) ^ ((row & 7) << 4))) = dk;
      bf16x8 dv = *(const bf16x8*)(Vbase + (size_t)(kv0 + row) * QKVN + sl * 8);
#pragma unroll
      for (int j = 0; j < 8; ++j)
        Vs[(sl * 8 + j) * 40 + row] = (u16)dv[j];
    }
    __syncthreads();

    if (kv0 <= q0 + 15) {  // wave-uniform: skip fully-masked tiles
      f32x4 sacc[2] = {};
#pragma unroll
      for (int c = 0; c < 4; ++c)
#pragma unroll
        for (int a = 0; a < 2; ++a) {
          int krow = a * 16 + fr;
          bf16x8 kf = *(const bf16x8*)((const char*)Ks + krow * 256 +
                                       ((c * 64 + fq * 16) ^ ((krow & 7) << 4)));
          sacc[a] = mfma16(qf[c], kf, sacc[a]);
        }
      float corr[4], pc[2][4];
#pragma unroll
      for (int r = 0; r < 4; ++r) {
        int qg = q0 + fq * 4 + r;
        float s0 = sacc[0][r] * SM_SCALE;
        float s1 = sacc[1][r] * SM_SCALE;
        if (kv0 + fr > qg) s0 = -1e30f;
        if (kv0 + 16 + fr > qg) s1 = -1e30f;
        float mx = fmaxf(s0, s1);
#pragma unroll
        for (int o = 8; o; o >>= 1) mx = fmaxf(mx, __shfl_xor(mx, o, 16));
        mx = fmaxf(mrow[r], mx);
        float p0 = (s0 < -1e29f) ? 0.0f : __expf(s0 - mx);
        float p1 = (s1 < -1e29f) ? 0.0f : __expf(s1 - mx);
        float sum = p0 + p1;
#pragma unroll
        for (int o = 8; o; o >>= 1) sum += __shfl_xor(sum, o, 16);
        corr[r] = __expf(mrow[r] - mx);
        lrow[r] = lrow[r] * corr[r] + sum;
        mrow[r] = mx;
        pc[0][r] = p0; pc[1][r] = p1;
      }
#pragma unroll
      for (int f = 0; f < 8; ++f) {
        outp[f][0] *= corr[0]; outp[f][1] *= corr[1];
        outp[f][2] *= corr[2]; outp[f][3] *= corr[3];
      }
      u16* pp = &Ps[wq][0];
#pragma unroll
      for (int a = 0; a < 2; ++a)
#pragma unroll
        for (int r = 0; r < 4; ++r)
          pp[(fq * 4 + r) * 40 + a * 16 + fr] = f2bf(pc[a][r]);
      asm volatile("s_waitcnt lgkmcnt(0)" ::: "memory");
      __builtin_amdgcn_sched_barrier(0);
      bf16x8 pa = *(const bf16x8*)&pp[fr * 40 + fq * 8];
#pragma unroll
      for (int f = 0; f < 8; ++f) {
        bf16x8 vb = *(const bf16x8*)&Vs[(f * 16 + fr) * 40 + fq * 8];
        outp[f] = mfma16(pa, vb, outp[f]);
      }
    }
  }
  float inv[4];
#pragma unroll
  for (int r = 0; r < 4; ++r) inv[r] = 1.0f / lrow[r];
#pragma unroll
  for (int f = 0; f < 8; ++f)
#pragma unroll
    for (int r = 0; r < 4; ++r)
      O[(tokbase + q0 + fq * 4 + r) * (size_t)DMODEL + h * HD + f * 16 + fr] =
          f2bf(outp[f][r] * inv[r]);
}

extern "C" void kernel_launch(void* const* d_in, const int* in_sizes, int n_in,
                              void* d_out, int out_size, void* d_ws, size_t ws_size,
                              hipStream_t stream) {
  const float* x  = (const float*)d_in[0];
  const float* Wq = (const float*)d_in[1];
  const float* Wk = (const float*)d_in[2];
  const float* Wv = (const float*)d_in[3];
  const float* Wo = (const float*)d_in[4];
  const float* qw = (const float*)d_in[5];
  const float* kw = (const float*)d_in[6];
  float* out = (float*)d_out;

  // Compact workspace (128 MiB total) with dead-buffer aliasing:
  //   [0,   32M)  xb   (bf16 x)      -- dead after GEMM1 -> reused as AO
  //   [32M, 80M)  Wqkvt (bf16 W^T)   -- dead after GEMM1 -> reused as Wot
  //   [80M, 128M) QKVb  (bf16 QKV)
  char* ws = (char*)d_ws;
  u16* xb    = (u16*)(ws);
  u16* Wqkvt = (u16*)(ws + 33554432);
  u16* QKVb  = (u16*)(ws + 83886080);
  u16* AO    = xb;
  u16* Wot   = Wqkvt;

  cvt_f32_bf16<<<2048, 256, 0, stream>>>(x, xb, (2 * SEQ * DMODEL) / 4);
  dim3 tb(32, 8);
  tconv<<<dim3(DMODEL / 32, DMODEL / 32), tb, 0, stream>>>(Wq, Wqkvt, DMODEL, 0);
  tconv<<<dim3((NKV * HD) / 32, DMODEL / 32), tb, 0, stream>>>(Wk, Wqkvt, NKV * HD, DMODEL);
  tconv<<<dim3((NKV * HD) / 32, DMODEL / 32), tb, 0, stream>>>(Wv, Wqkvt, NKV * HD, DMODEL + NKV * HD);

  gemm_bt<u16><<<dim3(4096 / 128, QKVN / 128), 256, 0, stream>>>(xb, Wqkvt, QKVb, 4096, QKVN, DMODEL);
  normrope<<<(4096 * 40) / 4, 256, 0, stream>>>(QKVb, qw, kw);

  // Wo transpose AFTER gemm1 (Wot aliases Wqkvt); attn output aliases xb.
  tconv<<<dim3(DMODEL / 32, DMODEL / 32), tb, 0, stream>>>(Wo, Wot, DMODEL, 0);
  attn<<<2048, 256, 0, stream>>>(QKVb, AO);
  gemm_bt<float><<<dim3(4096 / 128, DMODEL / 128), 256, 0, stream>>>(AO, Wot, out, 4096, DMODEL, DMODEL);
}

// Round 3
// 814.273 us; speedup vs baseline: 1.6277x; 1.6277x over previous
//
#include <hip/hip_runtime.h>

typedef unsigned short u16;
typedef __attribute__((ext_vector_type(8))) short bf16x8;
typedef __attribute__((ext_vector_type(4))) float f32x4;

#define NH 32
#define NKV 8
#define HD 128
#define SEQ 2048
#define DMODEL 4096
#define QKVN 6144
#define RMS_EPS 1e-6f
#define SM_SCALE 0.08838834764831845f
#define KVB 64

__device__ __forceinline__ u16 f2bf(float f) {
  unsigned int u = __float_as_uint(f);
  u += 0x7FFFu + ((u >> 16) & 1u);
  return (u16)(u >> 16);
}
__device__ __forceinline__ float bf2f(u16 b) {
  return __uint_as_float(((unsigned int)b) << 16);
}

__device__ __forceinline__ f32x4 mfma16(bf16x8 a, bf16x8 b, f32x4 c) {
  return __builtin_amdgcn_mfma_f32_16x16x32_bf16(a, b, c, 0, 0, 0);
}

__device__ __forceinline__ void stage16(const u16* g, u16* l) {
  __builtin_amdgcn_global_load_lds(
      (const __attribute__((address_space(1))) unsigned int*)g,
      (__attribute__((address_space(3))) unsigned int*)l, 16, 0, 0);
}

// ---------------- convert x: f32 -> bf16 ----------------
__global__ __launch_bounds__(256) void cvt_f32_bf16(const float* __restrict__ in,
                                                    u16* __restrict__ out, int n4) {
  int stride = gridDim.x * blockDim.x;
  for (int i = blockIdx.x * blockDim.x + threadIdx.x; i < n4; i += stride) {
    float4 v = ((const float4*)in)[i];
    ushort4 o;
    o.x = f2bf(v.x); o.y = f2bf(v.y); o.z = f2bf(v.z); o.w = f2bf(v.w);
    ((ushort4*)out)[i] = o;
  }
}

// ---------------- transpose-convert W[K=4096][N] f32 -> Wt[rowoff+N][4096] bf16 ----------------
__global__ __launch_bounds__(256) void tconv(const float* __restrict__ W, u16* __restrict__ Wt,
                                             int N, int rowoff) {
  __shared__ float t[32][33];
  int n0 = blockIdx.x * 32, k0 = blockIdx.y * 32;
  int tx = threadIdx.x, ty = threadIdx.y;  // (32,8)
#pragma unroll
  for (int i = 0; i < 4; ++i)
    t[ty + i * 8][tx] = W[(size_t)(k0 + ty + i * 8) * N + n0 + tx];
  __syncthreads();
#pragma unroll
  for (int i = 0; i < 4; ++i)
    Wt[(size_t)(rowoff + n0 + ty + i * 8) * DMODEL + k0 + tx] = f2bf(t[tx][ty + i * 8]);
}

// ---------------- GEMM: C[M][N] = A[M][K] * Bt[N][K]^T (bf16, m97 structure) ----------------
__device__ __forceinline__ void storeC(u16* p, float v) { *p = f2bf(v); }
__device__ __forceinline__ void storeC(float* p, float v) { *p = v; }

template <typename OutT>
__global__ __launch_bounds__(256) void gemm_bt(const u16* __restrict__ A, const u16* __restrict__ Bt,
                                               OutT* __restrict__ C, int M, int N, int K) {
  __shared__ __align__(16) u16 As[128 * 32];
  __shared__ __align__(16) u16 Bs[128 * 32];
  int m0 = blockIdx.x * 128, n0 = blockIdx.y * 128;
  int tid = threadIdx.x, wave = tid >> 6, lane = tid & 63;
  int wm = (wave >> 1) * 64, wn = (wave & 1) * 64;
  f32x4 acc[4][4] = {};
  int srow = lane >> 2;         // 16 rows per 1KB chunk, 4 lanes/row
  int scol = (lane & 3) * 8;    // 8 bf16 = 16B per lane
  int fr = lane & 15, fq = lane >> 4;

  for (int kb = 0; kb < K; kb += 32) {
    __syncthreads();
#pragma unroll
    for (int c = 0; c < 2; ++c) {
      int chunk = wave * 2 + c;  // 0..7
      int row = chunk * 16 + srow;
      stage16(A + (size_t)(m0 + row) * K + kb + scol, As + chunk * 512);
      stage16(Bt + (size_t)(n0 + row) * K + kb + scol, Bs + chunk * 512);
    }
    __syncthreads();
    bf16x8 af[4], bfv[4];
#pragma unroll
    for (int i = 0; i < 4; ++i) af[i] = *(const bf16x8*)&As[(wm + i * 16 + fr) * 32 + fq * 8];
#pragma unroll
    for (int j = 0; j < 4; ++j) bfv[j] = *(const bf16x8*)&Bs[(wn + j * 16 + fr) * 32 + fq * 8];
#pragma unroll
    for (int i = 0; i < 4; ++i)
#pragma unroll
      for (int j = 0; j < 4; ++j)
        acc[i][j] = mfma16(af[i], bfv[j], acc[i][j]);
  }
#pragma unroll
  for (int i = 0; i < 4; ++i)
#pragma unroll
    for (int j = 0; j < 4; ++j)
#pragma unroll
      for (int r = 0; r < 4; ++r) {
        int row = m0 + wm + i * 16 + fq * 4 + r;
        int col = n0 + wn + j * 16 + fr;
        storeC(&C[(size_t)row * N + col], acc[i][j][r]);
      }
}

// ---------------- RMSNorm + RoPE in place on Q/K slices of QKV ----------------
__global__ __launch_bounds__(256) void normrope(u16* __restrict__ QKV,
                                                const float* __restrict__ qw,
                                                const float* __restrict__ kw) {
  int wq = threadIdx.x >> 6, lane = threadIdx.x & 63;
  int gid = blockIdx.x * 4 + wq;
  int token = gid / 40, head = gid % 40;
  int pos = token & (SEQ - 1);
  const float* wrow;
  int col;
  if (head < NH) { wrow = qw; col = head * HD; }
  else           { wrow = kw; col = DMODEL + (head - NH) * HD; }
  u16* row = QKV + (size_t)token * QKVN + col;
  ushort2 xv = *(const ushort2*)(row + 2 * lane);
  float x1 = bf2f(xv.x), x2 = bf2f(xv.y);
  float ssq = x1 * x1 + x2 * x2;
#pragma unroll
  for (int o = 32; o; o >>= 1) ssq += __shfl_xor(ssq, o, 64);
  float rms = rsqrtf(ssq * (1.0f / HD) + RMS_EPS);
  float y1 = x1 * rms * wrow[2 * lane];
  float y2 = x2 * rms * wrow[2 * lane + 1];
  float freq = exp2f((float)lane * -0.20762050593046014f);
  float ang = (float)pos * freq;
  float s, c;
  sincosf(ang, &s, &c);
  ushort2 ov;
  ov.x = f2bf(y1 * c - y2 * s);
  ov.y = f2bf(y1 * s + y2 * c);
  *(ushort2*)(row + 2 * lane) = ov;
}

// ---------------- causal GQA flash attention (KVB=64, paired q-tiles) ----------------
// LDS (exactly 40960B -> 4 blocks/CU):
//   Ks[64][128]   row-major, 16B-slot swizzle key (row&7)    (staged via global_load_lds,
//                 source pre-swizzled so LDS dest stays linear)
//   Vs[128][64]   transposed [d][kv], byte = d*128 + ((2*kv) ^ (((d>>3)&7)<<4))
//   Ps[4][16][64] per-wave P, byte = q*128 + ((2*k) ^ ((q&7)<<4))
__global__ __launch_bounds__(256, 4) void attn(const u16* __restrict__ QKV, u16* __restrict__ O) {
  int bid = blockIdx.x;
  int pairi = bid & 15, h = (bid >> 4) & 31, b = bid >> 9;
  int tid = threadIdx.x, wave = tid >> 6, lane = tid & 63;
  int kvh = h >> 2;
  int fr = lane & 15, fq = lane >> 4;

  __shared__ __align__(16) u16 Ks[KVB * 128];
  __shared__ __align__(16) u16 Vs[128 * KVB];
  __shared__ __align__(16) u16 Ps[4][16 * KVB];

  size_t tokbase = (size_t)b * SEQ;
  const u16* Kbase = QKV + tokbase * QKVN + DMODEL + kvh * HD;
  const u16* Vbase = Kbase + NKV * HD;
  u16* pp = &Ps[wave][0];

  int srow = tid >> 4, sl = tid & 15;  // staging: row-offset (0..15), 16B slot

  for (int pass = 0; pass < 2; ++pass) {
    int qt = pass ? (31 - pairi) : pairi;
    int qbase = qt * 64;
    int q0 = qbase + wave * 16;

    bf16x8 qf[4];
    {
      const u16* qrow = QKV + (tokbase + q0 + fr) * QKVN + h * HD;
#pragma unroll
      for (int c = 0; c < 4; ++c) qf[c] = *(const bf16x8*)(qrow + c * 32 + fq * 8);
    }
    f32x4 outp[8] = {};
    float mrow[4] = {-1e30f, -1e30f, -1e30f, -1e30f};
    float lrow[4] = {0.f, 0.f, 0.f, 0.f};

    int kvend = qbase + 64;
    for (int kv0 = 0; kv0 < kvend; kv0 += KVB) {
      __syncthreads();
#pragma unroll
      for (int i = 0; i < 4; ++i) {
        int row = i * 16 + srow;  // local kv row 0..63
        // K: pre-swizzled global source -> linear LDS (lane-contiguous 16B)
        __builtin_amdgcn_global_load_lds(
            (const __attribute__((address_space(1))) unsigned int*)
                (Kbase + (size_t)(kv0 + row) * QKVN + ((sl ^ (row & 7)) * 8)),
            (__attribute__((address_space(3))) unsigned int*)(Ks + (i * 16 + wave * 4) * 128),
            16, 0, 0);
        // V: vector load, pair-pack kv/kv+1 via shfl, b32 transposed swizzled stores
        bf16x8 dv = *(const bf16x8*)(Vbase + (size_t)(kv0 + row) * QKVN + sl * 8);
        int4 dvi = *(int4*)&dv;
        int4 dpi;
        dpi.x = __shfl_xor(dvi.x, 16, 64);
        dpi.y = __shfl_xor(dvi.y, 16, 64);
        dpi.z = __shfl_xor(dvi.z, 16, 64);
        dpi.w = __shfl_xor(dvi.w, 16, 64);
        if (((tid >> 4) & 1) == 0) {  // even local row: write (kv, kv+1) pairs
          const u16* own = (const u16*)&dvi;
          const u16* par = (const u16*)&dpi;
#pragma unroll
          for (int j = 0; j < 8; ++j) {
            unsigned int wv = (unsigned int)own[j] | ((unsigned int)par[j] << 16);
            int d = sl * 8 + j;
            *(unsigned int*)((char*)Vs + d * 128 + ((2 * row) ^ ((sl & 7) << 4))) = wv;
          }
        }
      }
      __syncthreads();

      // QK^T: S[q=fq*4+r][k=a*16+fr] over d=128
      f32x4 sacc[4] = {};
#pragma unroll
      for (int c = 0; c < 4; ++c)
#pragma unroll
        for (int a = 0; a < 4; ++a) {
          int krow = a * 16 + fr;
          bf16x8 kf = *(const bf16x8*)((const char*)Ks + krow * 256 +
                                       ((c * 64 + fq * 16) ^ ((krow & 7) << 4)));
          sacc[a] = mfma16(qf[c], kf, sacc[a]);
        }

      float corr[4];
#pragma unroll
      for (int r = 0; r < 4; ++r) {
        int q_ = fq * 4 + r;
        int qg = q0 + q_;
        float s_[4];
        float mx = -1e30f;
#pragma unroll
        for (int a = 0; a < 4; ++a) {
          s_[a] = sacc[a][r] * SM_SCALE;
          if (kv0 + a * 16 + fr > qg) s_[a] = -1e30f;
          mx = fmaxf(mx, s_[a]);
        }
#pragma unroll
        for (int o = 8; o; o >>= 1) mx = fmaxf(mx, __shfl_xor(mx, o, 16));
        mx = fmaxf(mrow[r], mx);
        float sum = 0.f;
#pragma unroll
        for (int a = 0; a < 4; ++a) {
          float p = (s_[a] < -1e29f) ? 0.f : __expf(s_[a] - mx);
          sum += p;
          *(u16*)((char*)pp + q_ * 128 + ((2 * (a * 16 + fr)) ^ ((q_ & 7) << 4))) = f2bf(p);
        }
#pragma unroll
        for (int o = 8; o; o >>= 1) sum += __shfl_xor(sum, o, 16);
        corr[r] = __expf(mrow[r] - mx);
        lrow[r] = lrow[r] * corr[r] + sum;
        mrow[r] = mx;
      }
#pragma unroll
      for (int f = 0; f < 8; ++f) {
        outp[f][0] *= corr[0]; outp[f][1] *= corr[1];
        outp[f][2] *= corr[2]; outp[f][3] *= corr[3];
      }
      asm volatile("s_waitcnt lgkmcnt(0)" ::: "memory");
      __builtin_amdgcn_sched_barrier(0);
      bf16x8 pa[2];
#pragma unroll
      for (int c2 = 0; c2 < 2; ++c2)
        pa[c2] = *(const bf16x8*)((const char*)pp + fr * 128 +
                                  ((c2 * 64 + fq * 16) ^ ((fr & 7) << 4)));
#pragma unroll
      for (int f = 0; f < 8; ++f) {
        int d = f * 16 + fr;
#pragma unroll
        for (int c2 = 0; c2 < 2; ++c2) {
          bf16x8 vb = *(const bf16x8*)((const char*)Vs + d * 128 +
                                       ((c2 * 64 + fq * 16) ^ (((d >> 3) & 7) << 4)));
          outp[f] = mfma16(pa[c2], vb, outp[f]);
        }
      }
    }
    float inv[4];
#pragma unroll
    for (int r = 0; r < 4; ++r) inv[r] = 1.0f / lrow[r];
#pragma unroll
    for (int f = 0; f < 8; ++f)
#pragma unroll
      for (int r = 0; r < 4; ++r)
        O[(tokbase + q0 + fq * 4 + r) * (size_t)DMODEL + h * HD + f * 16 + fr] =
            f2bf(outp[f][r] * inv[r]);
  }
}

extern "C" void kernel_launch(void* const* d_in, const int* in_sizes, int n_in,
                              void* d_out, int out_size, void* d_ws, size_t ws_size,
                              hipStream_t stream) {
  const float* x  = (const float*)d_in[0];
  const float* Wq = (const float*)d_in[1];
  const float* Wk = (const float*)d_in[2];
  const float* Wv = (const float*)d_in[3];
  const float* Wo = (const float*)d_in[4];
  const float* qw = (const float*)d_in[5];
  const float* kw = (const float*)d_in[6];
  float* out = (float*)d_out;

  // Workspace (128 MiB) with dead-buffer aliasing:
  //   [0,   32M)  xb  (bf16 x)      -- dead after GEMM1 -> reused as AO
  //   [32M, 80M)  Wqkvt (bf16 W^T)  -- dead after GEMM1 -> reused as Wot
  //   [80M, 128M) QKVb (bf16 QKV)
  char* ws = (char*)d_ws;
  u16* xb    = (u16*)(ws);
  u16* Wqkvt = (u16*)(ws + 33554432);
  u16* QKVb  = (u16*)(ws + 83886080);
  u16* AO    = xb;
  u16* Wot   = Wqkvt;

  cvt_f32_bf16<<<2048, 256, 0, stream>>>(x, xb, (2 * SEQ * DMODEL) / 4);
  dim3 tb(32, 8);
  tconv<<<dim3(DMODEL / 32, DMODEL / 32), tb, 0, stream>>>(Wq, Wqkvt, DMODEL, 0);
  tconv<<<dim3((NKV * HD) / 32, DMODEL / 32), tb, 0, stream>>>(Wk, Wqkvt, NKV * HD, DMODEL);
  tconv<<<dim3((NKV * HD) / 32, DMODEL / 32), tb, 0, stream>>>(Wv, Wqkvt, NKV * HD, DMODEL + NKV * HD);

  gemm_bt<u16><<<dim3(4096 / 128, QKVN / 128), 256, 0, stream>>>(xb, Wqkvt, QKVb, 4096, QKVN, DMODEL);
  normrope<<<(4096 * 40) / 4, 256, 0, stream>>>(QKVb, qw, kw);

  tconv<<<dim3(DMODEL / 32, DMODEL / 32), tb, 0, stream>>>(Wo, Wot, DMODEL, 0);
  attn<<<1024, 256, 0, stream>>>(QKVb, AO);
  gemm_bt<float><<<dim3(4096 / 128, DMODEL / 128), 256, 0, stream>>>(AO, Wot, out, 4096, DMODEL, DMODEL);
}

// Round 6
// 770.994 us; speedup vs baseline: 1.7190x; 1.0561x over previous
//
#include <hip/hip_runtime.h>

typedef unsigned short u16;
typedef unsigned int u32;
typedef __attribute__((ext_vector_type(8))) short bf16x8;
typedef __attribute__((ext_vector_type(4))) float f32x4;

#define NH 32
#define NKV 8
#define HD 128
#define SEQ 2048
#define DMODEL 4096
#define QKVN 6144
#define RMS_EPS 1e-6f
#define SM_SCALE 0.08838834764831845f
#define KVB 64

#define AS1 __attribute__((address_space(1)))
#define AS3 __attribute__((address_space(3)))

__device__ __forceinline__ u16 f2bf(float f) {
  unsigned int u = __float_as_uint(f);
  u += 0x7FFFu + ((u >> 16) & 1u);
  return (u16)(u >> 16);
}
__device__ __forceinline__ float bf2f(u16 b) {
  return __uint_as_float(((unsigned int)b) << 16);
}

__device__ __forceinline__ f32x4 mfma16(bf16x8 a, bf16x8 b, f32x4 c) {
  return __builtin_amdgcn_mfma_f32_16x16x32_bf16(a, b, c, 0, 0, 0);
}

__device__ __forceinline__ void stage16(const u16* g, u16* l) {
  __builtin_amdgcn_global_load_lds((const AS1 u32*)g, (AS3 u32*)l, 16, 0, 0);
}

// ---------------- convert x: f32 -> bf16 ----------------
__global__ __launch_bounds__(256) void cvt_f32_bf16(const float* __restrict__ in,
                                                    u16* __restrict__ out, int n4) {
  int stride = gridDim.x * blockDim.x;
  for (int i = blockIdx.x * blockDim.x + threadIdx.x; i < n4; i += stride) {
    float4 v = ((const float4*)in)[i];
    ushort4 o;
    o.x = f2bf(v.x); o.y = f2bf(v.y); o.z = f2bf(v.z); o.w = f2bf(v.w);
    ((ushort4*)out)[i] = o;
  }
}

// ---------------- transpose-convert W[K=4096][N] f32 -> Wt[rowoff+N][4096] bf16 ----------------
__global__ __launch_bounds__(256) void tconv(const float* __restrict__ W, u16* __restrict__ Wt,
                                             int N, int rowoff) {
  __shared__ float t[32][33];
  int n0 = blockIdx.x * 32, k0 = blockIdx.y * 32;
  int tx = threadIdx.x, ty = threadIdx.y;  // (32,8)
#pragma unroll
  for (int i = 0; i < 4; ++i)
    t[ty + i * 8][tx] = W[(size_t)(k0 + ty + i * 8) * N + n0 + tx];
  __syncthreads();
#pragma unroll
  for (int i = 0; i < 4; ++i)
    Wt[(size_t)(rowoff + n0 + ty + i * 8) * DMODEL + k0 + tx] = f2bf(t[tx][ty + i * 8]);
}

// ---------------- GEMM (m97 structure + T1 XCD swizzle, 1D grid) ----------------
__device__ __forceinline__ void storeC(u16* p, float v) { *p = f2bf(v); }
__device__ __forceinline__ void storeC(float* p, float v) { *p = v; }

template <typename OutT>
__global__ __launch_bounds__(256) void gemm_bt(const u16* __restrict__ A, const u16* __restrict__ Bt,
                                               OutT* __restrict__ C, int M, int N, int K) {
  __shared__ __align__(16) u16 As[128 * 32];
  __shared__ __align__(16) u16 Bs[128 * 32];
  // XCD-aware bijective swizzle (nwg % 8 == 0 for both gemms)
  int nwg = gridDim.x, q8 = nwg >> 3, bid = blockIdx.x;
  int nid = (bid & 7) * q8 + (bid >> 3);
  int mt = M >> 7;
  int m0 = (nid % mt) * 128, n0 = (nid / mt) * 128;
  int tid = threadIdx.x, wave = tid >> 6, lane = tid & 63;
  int wm = (wave >> 1) * 64, wn = (wave & 1) * 64;
  f32x4 acc[4][4] = {};
  int srow = lane >> 2;
  int scol = (lane & 3) * 8;
  int fr = lane & 15, fq = lane >> 4;

  for (int kb = 0; kb < K; kb += 32) {
    __syncthreads();
#pragma unroll
    for (int c = 0; c < 2; ++c) {
      int chunk = wave * 2 + c;
      int row = chunk * 16 + srow;
      stage16(A + (size_t)(m0 + row) * K + kb + scol, As + chunk * 512);
      stage16(Bt + (size_t)(n0 + row) * K + kb + scol, Bs + chunk * 512);
    }
    __syncthreads();
    bf16x8 af[4], bfv[4];
#pragma unroll
    for (int i = 0; i < 4; ++i) af[i] = *(const bf16x8*)&As[(wm + i * 16 + fr) * 32 + fq * 8];
#pragma unroll
    for (int j = 0; j < 4; ++j) bfv[j] = *(const bf16x8*)&Bs[(wn + j * 16 + fr) * 32 + fq * 8];
    __builtin_amdgcn_s_setprio(1);
#pragma unroll
    for (int i = 0; i < 4; ++i)
#pragma unroll
      for (int j = 0; j < 4; ++j)
        acc[i][j] = mfma16(af[i], bfv[j], acc[i][j]);
    __builtin_amdgcn_s_setprio(0);
  }
#pragma unroll
  for (int i = 0; i < 4; ++i)
#pragma unroll
    for (int j = 0; j < 4; ++j)
#pragma unroll
      for (int r = 0; r < 4; ++r) {
        int row = m0 + wm + i * 16 + fq * 4 + r;
        int col = n0 + wn + j * 16 + fr;
        storeC(&C[(size_t)row * N + col], acc[i][j][r]);
      }
}

// ---------------- RMSNorm + RoPE in place on Q/K slices of QKV (proven version) ----------------
__global__ __launch_bounds__(256) void normrope(u16* __restrict__ QKV,
                                                const float* __restrict__ qw,
                                                const float* __restrict__ kw) {
  int wq = threadIdx.x >> 6, lane = threadIdx.x & 63;
  int gid = blockIdx.x * 4 + wq;
  int token = gid / 40, head = gid % 40;
  int pos = token & (SEQ - 1);
  const float* wrow;
  int col;
  if (head < NH) { wrow = qw; col = head * HD; }
  else           { wrow = kw; col = DMODEL + (head - NH) * HD; }
  u16* row = QKV + (size_t)token * QKVN + col;
  ushort2 xv = *(const ushort2*)(row + 2 * lane);
  float x1 = bf2f(xv.x), x2 = bf2f(xv.y);
  float ssq = x1 * x1 + x2 * x2;
#pragma unroll
  for (int o = 32; o; o >>= 1) ssq += __shfl_xor(ssq, o, 64);
  float rms = rsqrtf(ssq * (1.0f / HD) + RMS_EPS);
  float y1 = x1 * rms * wrow[2 * lane];
  float y2 = x2 * rms * wrow[2 * lane + 1];
  float freq = exp2f((float)lane * -0.20762050593046014f);
  float ang = (float)pos * freq;
  float s, c;
  sincosf(ang, &s, &c);
  ushort2 ov;
  ov.x = f2bf(y1 * c - y2 * s);
  ov.y = f2bf(y1 * s + y2 * c);
  *(ushort2*)(row + 2 * lane) = ov;
}

// ---------------- causal GQA flash attention (PROVEN round-3 kernel + T1/T5) ----------------
// LDS (exactly 40960B -> 4 blocks/CU):
//   Ks[64][128]   row-major, 16B-slot swizzle key (row&7)    (staged via global_load_lds,
//                 source pre-swizzled so LDS dest stays linear)
//   Vs[128][64]   transposed [d][kv], byte = d*128 + ((2*kv) ^ (((d>>3)&7)<<4))
//   Ps[4][16][64] per-wave P, byte = q*128 + ((2*k) ^ ((q&7)<<4))
__global__ __launch_bounds__(256, 4) void attn(const u16* __restrict__ QKV, u16* __restrict__ O) {
  // XCD-aware bijective swizzle: grid 1024 = 8 * 128
  int bid0 = blockIdx.x;
  int bid = (bid0 & 7) * 128 + (bid0 >> 3);
  int pairi = bid & 15, h = (bid >> 4) & 31, b = bid >> 9;
  int tid = threadIdx.x, wave = tid >> 6, lane = tid & 63;
  int kvh = h >> 2;
  int fr = lane & 15, fq = lane >> 4;

  __shared__ __align__(16) u16 Ks[KVB * 128];
  __shared__ __align__(16) u16 Vs[128 * KVB];
  __shared__ __align__(16) u16 Ps[4][16 * KVB];

  size_t tokbase = (size_t)b * SEQ;
  const u16* Kbase = QKV + tokbase * QKVN + DMODEL + kvh * HD;
  const u16* Vbase = Kbase + NKV * HD;
  u16* pp = &Ps[wave][0];

  int srow = tid >> 4, sl = tid & 15;  // staging: row-offset (0..15), 16B slot

  for (int pass = 0; pass < 2; ++pass) {
    int qt = pass ? (31 - pairi) : pairi;
    int qbase = qt * 64;
    int q0 = qbase + wave * 16;

    bf16x8 qf[4];
    {
      const u16* qrow = QKV + (tokbase + q0 + fr) * QKVN + h * HD;
#pragma unroll
      for (int c = 0; c < 4; ++c) qf[c] = *(const bf16x8*)(qrow + c * 32 + fq * 8);
    }
    f32x4 outp[8] = {};
    float mrow[4] = {-1e30f, -1e30f, -1e30f, -1e30f};
    float lrow[4] = {0.f, 0.f, 0.f, 0.f};

    int kvend = qbase + 64;
    for (int kv0 = 0; kv0 < kvend; kv0 += KVB) {
      __syncthreads();
#pragma unroll
      for (int i = 0; i < 4; ++i) {
        int row = i * 16 + srow;  // local kv row 0..63
        // K: pre-swizzled global source -> linear LDS (lane-contiguous 16B)
        __builtin_amdgcn_global_load_lds(
            (const AS1 u32*)(Kbase + (size_t)(kv0 + row) * QKVN + ((sl ^ (row & 7)) * 8)),
            (AS3 u32*)(Ks + (i * 16 + wave * 4) * 128), 16, 0, 0);
        // V: vector load, pair-pack kv/kv+1 via shfl, b32 transposed swizzled stores
        bf16x8 dv = *(const bf16x8*)(Vbase + (size_t)(kv0 + row) * QKVN + sl * 8);
        int4 dvi = *(int4*)&dv;
        int4 dpi;
        dpi.x = __shfl_xor(dvi.x, 16, 64);
        dpi.y = __shfl_xor(dvi.y, 16, 64);
        dpi.z = __shfl_xor(dvi.z, 16, 64);
        dpi.w = __shfl_xor(dvi.w, 16, 64);
        if (((tid >> 4) & 1) == 0) {  // even local row: write (kv, kv+1) pairs
          const u16* own = (const u16*)&dvi;
          const u16* par = (const u16*)&dpi;
#pragma unroll
          for (int j = 0; j < 8; ++j) {
            unsigned int wv = (unsigned int)own[j] | ((unsigned int)par[j] << 16);
            int d = sl * 8 + j;
            *(unsigned int*)((char*)Vs + d * 128 + ((2 * row) ^ ((sl & 7) << 4))) = wv;
          }
        }
      }
      __syncthreads();

      if (kv0 <= q0 + 15) {  // wave-uniform: skip fully-masked tiles
        // QK^T: S[q=fq*4+r][k=a*16+fr] over d=128
        f32x4 sacc[4] = {};
        __builtin_amdgcn_s_setprio(1);
#pragma unroll
        for (int c = 0; c < 4; ++c)
#pragma unroll
          for (int a = 0; a < 4; ++a) {
            int krow = a * 16 + fr;
            bf16x8 kf = *(const bf16x8*)((const char*)Ks + krow * 256 +
                                         ((c * 64 + fq * 16) ^ ((krow & 7) << 4)));
            sacc[a] = mfma16(qf[c], kf, sacc[a]);
          }
        __builtin_amdgcn_s_setprio(0);

        float corr[4];
#pragma unroll
        for (int r = 0; r < 4; ++r) {
          int q_ = fq * 4 + r;
          int qg = q0 + q_;
          float s_[4];
          float mx = -1e30f;
#pragma unroll
          for (int a = 0; a < 4; ++a) {
            s_[a] = sacc[a][r] * SM_SCALE;
            if (kv0 + a * 16 + fr > qg) s_[a] = -1e30f;
            mx = fmaxf(mx, s_[a]);
          }
#pragma unroll
          for (int o = 8; o; o >>= 1) mx = fmaxf(mx, __shfl_xor(mx, o, 16));
          mx = fmaxf(mrow[r], mx);
          float sum = 0.f;
#pragma unroll
          for (int a = 0; a < 4; ++a) {
            float p = (s_[a] < -1e29f) ? 0.f : __expf(s_[a] - mx);
            sum += p;
            *(u16*)((char*)pp + q_ * 128 + ((2 * (a * 16 + fr)) ^ ((q_ & 7) << 4))) = f2bf(p);
          }
#pragma unroll
          for (int o = 8; o; o >>= 1) sum += __shfl_xor(sum, o, 16);
          corr[r] = __expf(mrow[r] - mx);
          lrow[r] = lrow[r] * corr[r] + sum;
          mrow[r] = mx;
        }
#pragma unroll
        for (int f = 0; f < 8; ++f) {
          outp[f][0] *= corr[0]; outp[f][1] *= corr[1];
          outp[f][2] *= corr[2]; outp[f][3] *= corr[3];
        }
        asm volatile("s_waitcnt lgkmcnt(0)" ::: "memory");
        __builtin_amdgcn_sched_barrier(0);
        bf16x8 pa[2];
#pragma unroll
        for (int c2 = 0; c2 < 2; ++c2)
          pa[c2] = *(const bf16x8*)((const char*)pp + fr * 128 +
                                    ((c2 * 64 + fq * 16) ^ ((fr & 7) << 4)));
        __builtin_amdgcn_s_setprio(1);
#pragma unroll
        for (int f = 0; f < 8; ++f) {
          int d = f * 16 + fr;
#pragma unroll
          for (int c2 = 0; c2 < 2; ++c2) {
            bf16x8 vb = *(const bf16x8*)((const char*)Vs + d * 128 +
                                         ((c2 * 64 + fq * 16) ^ (((d >> 3) & 7) << 4)));
            outp[f] = mfma16(pa[c2], vb, outp[f]);
          }
        }
        __builtin_amdgcn_s_setprio(0);
      }
    }
    float inv[4];
#pragma unroll
    for (int r = 0; r < 4; ++r) inv[r] = 1.0f / lrow[r];
#pragma unroll
    for (int f = 0; f < 8; ++f)
#pragma unroll
      for (int r = 0; r < 4; ++r)
        O[(tokbase + q0 + fq * 4 + r) * (size_t)DMODEL + h * HD + f * 16 + fr] =
            f2bf(outp[f][r] * inv[r]);
  }
}

extern "C" void kernel_launch(void* const* d_in, const int* in_sizes, int n_in,
                              void* d_out, int out_size, void* d_ws, size_t ws_size,
                              hipStream_t stream) {
  const float* x  = (const float*)d_in[0];
  const float* Wq = (const float*)d_in[1];
  const float* Wk = (const float*)d_in[2];
  const float* Wv = (const float*)d_in[3];
  const float* Wo = (const float*)d_in[4];
  const float* qw = (const float*)d_in[5];
  const float* kw = (const float*)d_in[6];
  float* out = (float*)d_out;

  // Workspace (128 MiB) with dead-buffer aliasing:
  //   [0,   32M)  xb  (bf16 x)      -- dead after GEMM1 -> reused as AO
  //   [32M, 80M)  Wqkvt (bf16 W^T)  -- dead after GEMM1 -> reused as Wot
  //   [80M, 128M) QKVb (bf16 QKV)
  char* ws = (char*)d_ws;
  u16* xb    = (u16*)(ws);
  u16* Wqkvt = (u16*)(ws + 33554432);
  u16* QKVb  = (u16*)(ws + 83886080);
  u16* AO    = xb;
  u16* Wot   = Wqkvt;

  cvt_f32_bf16<<<2048, 256, 0, stream>>>(x, xb, (2 * SEQ * DMODEL) / 4);
  dim3 tb(32, 8);
  tconv<<<dim3(DMODEL / 32, DMODEL / 32), tb, 0, stream>>>(Wq, Wqkvt, DMODEL, 0);
  tconv<<<dim3((NKV * HD) / 32, DMODEL / 32), tb, 0, stream>>>(Wk, Wqkvt, NKV * HD, DMODEL);
  tconv<<<dim3((NKV * HD) / 32, DMODEL / 32), tb, 0, stream>>>(Wv, Wqkvt, NKV * HD, DMODEL + NKV * HD);

  gemm_bt<u16><<<(4096 / 128) * (QKVN / 128), 256, 0, stream>>>(xb, Wqkvt, QKVb, 4096, QKVN, DMODEL);
  normrope<<<(4096 * 40) / 4, 256, 0, stream>>>(QKVb, qw, kw);

  tconv<<<dim3(DMODEL / 32, DMODEL / 32), tb, 0, stream>>>(Wo, Wot, DMODEL, 0);
  attn<<<1024, 256, 0, stream>>>(QKVb, AO);
  gemm_bt<float><<<(4096 / 128) * (DMODEL / 128), 256, 0, stream>>>(AO, Wot, out, 4096, DMODEL, DMODEL);
}

// Round 7
// 748.003 us; speedup vs baseline: 1.7719x; 1.0307x over previous
//
#include <hip/hip_runtime.h>

typedef unsigned short u16;
typedef unsigned int u32;
typedef __attribute__((ext_vector_type(8))) short bf16x8;
typedef __attribute__((ext_vector_type(4))) float f32x4;

#define NH 32
#define NKV 8
#define HD 128
#define SEQ 2048
#define DMODEL 4096
#define QKVN 6144
#define RMS_EPS 1e-6f
#define SM_SCALE 0.08838834764831845f
#define KVB 64

#define AS1 __attribute__((address_space(1)))
#define AS3 __attribute__((address_space(3)))

__device__ __forceinline__ u16 f2bf(float f) {
  unsigned int u = __float_as_uint(f);
  u += 0x7FFFu + ((u >> 16) & 1u);
  return (u16)(u >> 16);
}
__device__ __forceinline__ float bf2f(u16 b) {
  return __uint_as_float(((unsigned int)b) << 16);
}

__device__ __forceinline__ f32x4 mfma16(bf16x8 a, bf16x8 b, f32x4 c) {
  return __builtin_amdgcn_mfma_f32_16x16x32_bf16(a, b, c, 0, 0, 0);
}

__device__ __forceinline__ void stage16(const u16* g, u16* l) {
  __builtin_amdgcn_global_load_lds((const AS1 u32*)g, (AS3 u32*)l, 16, 0, 0);
}

// ---------------- convert x: f32 -> bf16 ----------------
__global__ __launch_bounds__(256) void cvt_f32_bf16(const float* __restrict__ in,
                                                    u16* __restrict__ out, int n4) {
  int stride = gridDim.x * blockDim.x;
  for (int i = blockIdx.x * blockDim.x + threadIdx.x; i < n4; i += stride) {
    float4 v = ((const float4*)in)[i];
    ushort4 o;
    o.x = f2bf(v.x); o.y = f2bf(v.y); o.z = f2bf(v.z); o.w = f2bf(v.w);
    ((ushort4*)out)[i] = o;
  }
}

// ---------------- transpose-convert W[K=4096][N] f32 -> Wt[rowoff+N][4096] bf16 ----------------
__global__ __launch_bounds__(256) void tconv(const float* __restrict__ W, u16* __restrict__ Wt,
                                             int N, int rowoff) {
  __shared__ float t[32][33];
  int n0 = blockIdx.x * 32, k0 = blockIdx.y * 32;
  int tx = threadIdx.x, ty = threadIdx.y;  // (32,8)
#pragma unroll
  for (int i = 0; i < 4; ++i)
    t[ty + i * 8][tx] = W[(size_t)(k0 + ty + i * 8) * N + n0 + tx];
  __syncthreads();
#pragma unroll
  for (int i = 0; i < 4; ++i)
    Wt[(size_t)(rowoff + n0 + ty + i * 8) * DMODEL + k0 + tx] = f2bf(t[tx][ty + i * 8]);
}

// ---------------- GEMM (m97 structure + T1 XCD swizzle, 1D grid) ----------------
__device__ __forceinline__ void storeC(u16* p, float v) { *p = f2bf(v); }
__device__ __forceinline__ void storeC(float* p, float v) { *p = v; }

template <typename OutT>
__global__ __launch_bounds__(256) void gemm_bt(const u16* __restrict__ A, const u16* __restrict__ Bt,
                                               OutT* __restrict__ C, int M, int N, int K) {
  __shared__ __align__(16) u16 As[128 * 32];
  __shared__ __align__(16) u16 Bs[128 * 32];
  // XCD-aware bijective swizzle (nwg % 8 == 0 for both gemms)
  int nwg = gridDim.x, q8 = nwg >> 3, bid = blockIdx.x;
  int nid = (bid & 7) * q8 + (bid >> 3);
  int mt = M >> 7;
  int m0 = (nid % mt) * 128, n0 = (nid / mt) * 128;
  int tid = threadIdx.x, wave = tid >> 6, lane = tid & 63;
  int wm = (wave >> 1) * 64, wn = (wave & 1) * 64;
  f32x4 acc[4][4] = {};
  int srow = lane >> 2;
  int scol = (lane & 3) * 8;
  int fr = lane & 15, fq = lane >> 4;

  for (int kb = 0; kb < K; kb += 32) {
    __syncthreads();
#pragma unroll
    for (int c = 0; c < 2; ++c) {
      int chunk = wave * 2 + c;
      int row = chunk * 16 + srow;
      stage16(A + (size_t)(m0 + row) * K + kb + scol, As + chunk * 512);
      stage16(Bt + (size_t)(n0 + row) * K + kb + scol, Bs + chunk * 512);
    }
    __syncthreads();
    bf16x8 af[4], bfv[4];
#pragma unroll
    for (int i = 0; i < 4; ++i) af[i] = *(const bf16x8*)&As[(wm + i * 16 + fr) * 32 + fq * 8];
#pragma unroll
    for (int j = 0; j < 4; ++j) bfv[j] = *(const bf16x8*)&Bs[(wn + j * 16 + fr) * 32 + fq * 8];
    __builtin_amdgcn_s_setprio(1);
#pragma unroll
    for (int i = 0; i < 4; ++i)
#pragma unroll
      for (int j = 0; j < 4; ++j)
        acc[i][j] = mfma16(af[i], bfv[j], acc[i][j]);
    __builtin_amdgcn_s_setprio(0);
  }
#pragma unroll
  for (int i = 0; i < 4; ++i)
#pragma unroll
    for (int j = 0; j < 4; ++j)
#pragma unroll
      for (int r = 0; r < 4; ++r) {
        int row = m0 + wm + i * 16 + fq * 4 + r;
        int col = n0 + wn + j * 16 + fr;
        storeC(&C[(size_t)row * N + col], acc[i][j][r]);
      }
}

// ---------------- RMSNorm + RoPE (Q pre-scaled by SM_SCALE) ----------------
__global__ __launch_bounds__(256) void normrope(u16* __restrict__ QKV,
                                                const float* __restrict__ qw,
                                                const float* __restrict__ kw) {
  int wq = threadIdx.x >> 6, lane = threadIdx.x & 63;
  int gid = blockIdx.x * 4 + wq;
  int token = gid / 40, head = gid % 40;
  int pos = token & (SEQ - 1);
  const float* wrow;
  int col;
  float sc;
  if (head < NH) { wrow = qw; col = head * HD; sc = SM_SCALE; }
  else           { wrow = kw; col = DMODEL + (head - NH) * HD; sc = 1.0f; }
  u16* row = QKV + (size_t)token * QKVN + col;
  ushort2 xv = *(const ushort2*)(row + 2 * lane);
  float x1 = bf2f(xv.x), x2 = bf2f(xv.y);
  float ssq = x1 * x1 + x2 * x2;
#pragma unroll
  for (int o = 32; o; o >>= 1) ssq += __shfl_xor(ssq, o, 64);
  float rms = rsqrtf(ssq * (1.0f / HD) + RMS_EPS);
  float y1 = x1 * rms * wrow[2 * lane] * sc;
  float y2 = x2 * rms * wrow[2 * lane + 1] * sc;
  float freq = exp2f((float)lane * -0.20762050593046014f);
  float ang = (float)pos * freq;
  float s, c;
  sincosf(ang, &s, &c);
  ushort2 ov;
  ov.x = f2bf(y1 * c - y2 * s);
  ov.y = f2bf(y1 * s + y2 * c);
  *(ushort2*)(row + 2 * lane) = ov;
}

// ---------------- causal GQA flash attention (r6 compute + K/V double-buffer) ----------------
// LDS 73728B -> 2 blocks/CU:
//   Ks[2][64][128]  row-major, 16B-slot swizzle key (row&7), staged via global_load_lds
//                   with pre-swizzled global source (LDS dest linear)
//   Vs[2][128][64]  transposed [d][kv], byte = d*128 + ((2*kv) ^ (((d>>3)&7)<<4))
//   Ps[4][16][64]   per-wave P, byte = q*128 + ((2*k) ^ ((q&7)<<4))
// Pipeline per tile: {loadV(next); stageK(next)} -> compute(cur) -> packV(next) -> barrier.
// V loads issued BEFORE K gload_lds so packV's vmcnt wait leaves K in flight; the single
// __syncthreads per tile drains vmcnt+lgkm before buffer swap.
__global__ __launch_bounds__(256, 2) void attn(const u16* __restrict__ QKV, u16* __restrict__ O) {
  // XCD-aware bijective swizzle: grid 1024 = 8 * 128
  int bid0 = blockIdx.x;
  int bid = (bid0 & 7) * 128 + (bid0 >> 3);
  int pairi = bid & 15, h = (bid >> 4) & 31, b = bid >> 9;
  int tid = threadIdx.x, wave = tid >> 6, lane = tid & 63;
  int kvh = h >> 2;
  int fr = lane & 15, fq = lane >> 4;

  __shared__ __align__(16) u16 Ks[2][KVB * 128];
  __shared__ __align__(16) u16 Vs[2][128 * KVB];
  __shared__ __align__(16) u16 Ps[4][16 * KVB];

  size_t tokbase = (size_t)b * SEQ;
  const u16* Kbase = QKV + tokbase * QKVN + DMODEL + kvh * HD;
  const u16* Vbase = Kbase + NKV * HD;
  u16* pp = &Ps[wave][0];

  int srow = tid >> 4, sl = tid & 15;  // staging: row-offset (0..15), 16B slot

  int4 vreg[4];
  auto loadV = [&](int kv0) {
#pragma unroll
    for (int i = 0; i < 4; ++i) {
      int row = i * 16 + srow;
      vreg[i] = *(const int4*)(Vbase + (size_t)(kv0 + row) * QKVN + sl * 8);
    }
  };
  auto stageK = [&](int buf, int kv0) {
#pragma unroll
    for (int i = 0; i < 4; ++i) {
      int row = i * 16 + srow;
      __builtin_amdgcn_global_load_lds(
          (const AS1 u32*)(Kbase + (size_t)(kv0 + row) * QKVN + ((sl ^ (row & 7)) * 8)),
          (AS3 u32*)(&Ks[buf][0] + (i * 16 + wave * 4) * 128), 16, 0, 0);
    }
  };
  auto packV = [&](int buf) {
#pragma unroll
    for (int i = 0; i < 4; ++i) {
      int row = i * 16 + srow;
      int4 dvi = vreg[i];
      int4 dpi;
      dpi.x = __shfl_xor(dvi.x, 16, 64);
      dpi.y = __shfl_xor(dvi.y, 16, 64);
      dpi.z = __shfl_xor(dvi.z, 16, 64);
      dpi.w = __shfl_xor(dvi.w, 16, 64);
      if (((tid >> 4) & 1) == 0) {  // even local row: write (kv, kv+1) pairs
        const u16* own = (const u16*)&dvi;
        const u16* par = (const u16*)&dpi;
#pragma unroll
        for (int j = 0; j < 8; ++j) {
          unsigned int wv = (unsigned int)own[j] | ((unsigned int)par[j] << 16);
          int d = sl * 8 + j;
          *(unsigned int*)((char*)&Vs[buf][0] + d * 128 + ((2 * row) ^ ((sl & 7) << 4))) = wv;
        }
      }
    }
  };

  for (int pass = 0; pass < 2; ++pass) {
    int qt = pass ? (31 - pairi) : pairi;
    int qbase = qt * 64;
    int q0 = qbase + wave * 16;

    bf16x8 qf[4];
    {
      const u16* qrow = QKV + (tokbase + q0 + fr) * QKVN + h * HD;
#pragma unroll
      for (int c = 0; c < 4; ++c) qf[c] = *(const bf16x8*)(qrow + c * 32 + fq * 8);
    }
    f32x4 outp[8] = {};
    float mrow[4] = {-1e30f, -1e30f, -1e30f, -1e30f};
    float lrow[4] = {0.f, 0.f, 0.f, 0.f};

    int nt = qt + 1;  // kv tiles

    // prologue: tile 0 into buffer 0
    loadV(0);
    stageK(0, 0);
    packV(0);
    __syncthreads();  // drains K0 (vmcnt) + V0 (lgkm)

    for (int t = 0; t < nt; ++t) {
      int cur = t & 1, nxt = cur ^ 1;
      bool more = (t + 1) < nt;
      if (more) {
        loadV((t + 1) * 64);     // plain vector loads first (vmcnt ordering)
        stageK(nxt, (t + 1) * 64);  // gload_lds after; stays in flight thru compute
      }
      int kv0 = t * 64;

      if (kv0 <= q0 + 15) {  // wave-uniform: skip fully-masked tiles
        const u16* Ksb = &Ks[cur][0];
        const u16* Vsb = &Vs[cur][0];
        // QK^T: S[q=fq*4+r][k=a*16+fr] over d=128
        f32x4 sacc[4] = {};
        __builtin_amdgcn_s_setprio(1);
#pragma unroll
        for (int c = 0; c < 4; ++c)
#pragma unroll
          for (int a = 0; a < 4; ++a) {
            int krow = a * 16 + fr;
            bf16x8 kf = *(const bf16x8*)((const char*)Ksb + krow * 256 +
                                         ((c * 64 + fq * 16) ^ ((krow & 7) << 4)));
            sacc[a] = mfma16(qf[c], kf, sacc[a]);
          }
        __builtin_amdgcn_s_setprio(0);

        float corr[4];
#pragma unroll
        for (int r = 0; r < 4; ++r) {
          int q_ = fq * 4 + r;
          int qg = q0 + q_;
          float s_[4];
          float mx = -1e30f;
#pragma unroll
          for (int a = 0; a < 4; ++a) {
            s_[a] = sacc[a][r];  // SM_SCALE pre-applied to Q in normrope
            if (kv0 + a * 16 + fr > qg) s_[a] = -1e30f;
            mx = fmaxf(mx, s_[a]);
          }
#pragma unroll
          for (int o = 8; o; o >>= 1) mx = fmaxf(mx, __shfl_xor(mx, o, 16));
          mx = fmaxf(mrow[r], mx);
          float sum = 0.f;
#pragma unroll
          for (int a = 0; a < 4; ++a) {
            float p = (s_[a] < -1e29f) ? 0.f : __expf(s_[a] - mx);
            sum += p;
            *(u16*)((char*)pp + q_ * 128 + ((2 * (a * 16 + fr)) ^ ((q_ & 7) << 4))) = f2bf(p);
          }
#pragma unroll
          for (int o = 8; o; o >>= 1) sum += __shfl_xor(sum, o, 16);
          corr[r] = __expf(mrow[r] - mx);
          lrow[r] = lrow[r] * corr[r] + sum;
          mrow[r] = mx;
        }
#pragma unroll
        for (int f = 0; f < 8; ++f) {
          outp[f][0] *= corr[0]; outp[f][1] *= corr[1];
          outp[f][2] *= corr[2]; outp[f][3] *= corr[3];
        }
        asm volatile("s_waitcnt lgkmcnt(0)" ::: "memory");
        __builtin_amdgcn_sched_barrier(0);
        bf16x8 pa[2];
#pragma unroll
        for (int c2 = 0; c2 < 2; ++c2)
          pa[c2] = *(const bf16x8*)((const char*)pp + fr * 128 +
                                    ((c2 * 64 + fq * 16) ^ ((fr & 7) << 4)));
        __builtin_amdgcn_s_setprio(1);
#pragma unroll
        for (int f = 0; f < 8; ++f) {
          int d = f * 16 + fr;
#pragma unroll
          for (int c2 = 0; c2 < 2; ++c2) {
            bf16x8 vb = *(const bf16x8*)((const char*)Vsb + d * 128 +
                                         ((c2 * 64 + fq * 16) ^ (((d >> 3) & 7) << 4)));
            outp[f] = mfma16(pa[c2], vb, outp[f]);
          }
        }
        __builtin_amdgcn_s_setprio(0);
      }

      if (more) packV(nxt);  // waits only V loads (vmcnt leaves K in flight)
      __syncthreads();       // drains K-next vmcnt + V-next lgkm; all waves done with cur
    }

    float inv[4];
#pragma unroll
    for (int r = 0; r < 4; ++r) inv[r] = 1.0f / lrow[r];
#pragma unroll
    for (int f = 0; f < 8; ++f)
#pragma unroll
      for (int r = 0; r < 4; ++r)
        O[(tokbase + q0 + fq * 4 + r) * (size_t)DMODEL + h * HD + f * 16 + fr] =
            f2bf(outp[f][r] * inv[r]);
  }
}

extern "C" void kernel_launch(void* const* d_in, const int* in_sizes, int n_in,
                              void* d_out, int out_size, void* d_ws, size_t ws_size,
                              hipStream_t stream) {
  const float* x  = (const float*)d_in[0];
  const float* Wq = (const float*)d_in[1];
  const float* Wk = (const float*)d_in[2];
  const float* Wv = (const float*)d_in[3];
  const float* Wo = (const float*)d_in[4];
  const float* qw = (const float*)d_in[5];
  const float* kw = (const float*)d_in[6];
  float* out = (float*)d_out;

  // Workspace (128 MiB) with dead-buffer aliasing:
  //   [0,   32M)  xb  (bf16 x)      -- dead after GEMM1 -> reused as AO
  //   [32M, 80M)  Wqkvt (bf16 W^T)  -- dead after GEMM1 -> reused as Wot
  //   [80M, 128M) QKVb (bf16 QKV)
  char* ws = (char*)d_ws;
  u16* xb    = (u16*)(ws);
  u16* Wqkvt = (u16*)(ws + 33554432);
  u16* QKVb  = (u16*)(ws + 83886080);
  u16* AO    = xb;
  u16* Wot   = Wqkvt;

  cvt_f32_bf16<<<2048, 256, 0, stream>>>(x, xb, (2 * SEQ * DMODEL) / 4);
  dim3 tb(32, 8);
  tconv<<<dim3(DMODEL / 32, DMODEL / 32), tb, 0, stream>>>(Wq, Wqkvt, DMODEL, 0);
  tconv<<<dim3((NKV * HD) / 32, DMODEL / 32), tb, 0, stream>>>(Wk, Wqkvt, NKV * HD, DMODEL);
  tconv<<<dim3((NKV * HD) / 32, DMODEL / 32), tb, 0, stream>>>(Wv, Wqkvt, NKV * HD, DMODEL + NKV * HD);

  gemm_bt<u16><<<(4096 / 128) * (QKVN / 128), 256, 0, stream>>>(xb, Wqkvt, QKVb, 4096, QKVN, DMODEL);
  normrope<<<(4096 * 40) / 4, 256, 0, stream>>>(QKVb, qw, kw);

  tconv<<<dim3(DMODEL / 32, DMODEL / 32), tb, 0, stream>>>(Wo, Wot, DMODEL, 0);
  attn<<<1024, 256, 0, stream>>>(QKVb, AO);
  gemm_bt<float><<<(4096 / 128) * (DMODEL / 128), 256, 0, stream>>>(AO, Wot, out, 4096, DMODEL, DMODEL);
}

// Round 8
// 645.572 us; speedup vs baseline: 2.0530x; 1.1587x over previous
//
#include <hip/hip_runtime.h>

typedef unsigned short u16;
typedef unsigned int u32;
typedef __attribute__((ext_vector_type(8))) short bf16x8;
typedef __attribute__((ext_vector_type(4))) float f32x4;
typedef __attribute__((ext_vector_type(16))) float f32x16;

#define NH 32
#define NKV 8
#define HD 128
#define SEQ 2048
#define DMODEL 4096
#define QKVN 6144
#define RMS_EPS 1e-6f
#define SM_SCALE 0.08838834764831845f
#define NEG_INF -1e30f

#define AS1 __attribute__((address_space(1)))
#define AS3 __attribute__((address_space(3)))

__device__ __forceinline__ u16 f2bf(float f) {
  unsigned int u = __float_as_uint(f);
  u += 0x7FFFu + ((u >> 16) & 1u);
  return (u16)(u >> 16);
}
__device__ __forceinline__ float bf2f(u16 b) {
  return __uint_as_float(((unsigned int)b) << 16);
}
__device__ __forceinline__ u32 packbf(float lo, float hi) {
  u32 a = __float_as_uint(lo) + 0x8000u;
  u32 b = __float_as_uint(hi) + 0x8000u;
  return __builtin_amdgcn_perm(b, a, 0x07060302u);
}

__device__ __forceinline__ f32x4 mfma16(bf16x8 a, bf16x8 b, f32x4 c) {
  return __builtin_amdgcn_mfma_f32_16x16x32_bf16(a, b, c, 0, 0, 0);
}
__device__ __forceinline__ f32x16 mfma32(bf16x8 a, bf16x8 b, f32x16 c) {
  return __builtin_amdgcn_mfma_f32_32x32x16_bf16(a, b, c, 0, 0, 0);
}

__device__ __forceinline__ void stage16(const u16* g, u16* l) {
  __builtin_amdgcn_global_load_lds((const AS1 u32*)g, (AS3 u32*)l, 16, 0, 0);
}

// ---------------- convert x: f32 -> bf16 ----------------
__global__ __launch_bounds__(256) void cvt_f32_bf16(const float* __restrict__ in,
                                                    u16* __restrict__ out, int n4) {
  int stride = gridDim.x * blockDim.x;
  for (int i = blockIdx.x * blockDim.x + threadIdx.x; i < n4; i += stride) {
    float4 v = ((const float4*)in)[i];
    ushort4 o;
    o.x = f2bf(v.x); o.y = f2bf(v.y); o.z = f2bf(v.z); o.w = f2bf(v.w);
    ((ushort4*)out)[i] = o;
  }
}

// ---------------- transpose-convert W[K=4096][N] f32 -> Wt[rowoff+N][4096] bf16 ----------------
__global__ __launch_bounds__(256) void tconv(const float* __restrict__ W, u16* __restrict__ Wt,
                                             int N, int rowoff) {
  __shared__ float t[32][33];
  int n0 = blockIdx.x * 32, k0 = blockIdx.y * 32;
  int tx = threadIdx.x, ty = threadIdx.y;  // (32,8)
#pragma unroll
  for (int i = 0; i < 4; ++i)
    t[ty + i * 8][tx] = W[(size_t)(k0 + ty + i * 8) * N + n0 + tx];
  __syncthreads();
#pragma unroll
  for (int i = 0; i < 4; ++i)
    Wt[(size_t)(rowoff + n0 + ty + i * 8) * DMODEL + k0 + tx] = f2bf(t[tx][ty + i * 8]);
}

// ---------------- GEMM (m97 structure + T1 XCD swizzle, 1D grid) ----------------
__device__ __forceinline__ void storeC(u16* p, float v) { *p = f2bf(v); }
__device__ __forceinline__ void storeC(float* p, float v) { *p = v; }

template <typename OutT>
__global__ __launch_bounds__(256) void gemm_bt(const u16* __restrict__ A, const u16* __restrict__ Bt,
                                               OutT* __restrict__ C, int M, int N, int K) {
  __shared__ __align__(16) u16 As[128 * 32];
  __shared__ __align__(16) u16 Bs[128 * 32];
  int nwg = gridDim.x, q8 = nwg >> 3, bid = blockIdx.x;
  int nid = (bid & 7) * q8 + (bid >> 3);
  int mt = M >> 7;
  int m0 = (nid % mt) * 128, n0 = (nid / mt) * 128;
  int tid = threadIdx.x, wave = tid >> 6, lane = tid & 63;
  int wm = (wave >> 1) * 64, wn = (wave & 1) * 64;
  f32x4 acc[4][4] = {};
  int srow = lane >> 2;
  int scol = (lane & 3) * 8;
  int fr = lane & 15, fq = lane >> 4;

  for (int kb = 0; kb < K; kb += 32) {
    __syncthreads();
#pragma unroll
    for (int c = 0; c < 2; ++c) {
      int chunk = wave * 2 + c;
      int row = chunk * 16 + srow;
      stage16(A + (size_t)(m0 + row) * K + kb + scol, As + chunk * 512);
      stage16(Bt + (size_t)(n0 + row) * K + kb + scol, Bs + chunk * 512);
    }
    __syncthreads();
    bf16x8 af[4], bfv[4];
#pragma unroll
    for (int i = 0; i < 4; ++i) af[i] = *(const bf16x8*)&As[(wm + i * 16 + fr) * 32 + fq * 8];
#pragma unroll
    for (int j = 0; j < 4; ++j) bfv[j] = *(const bf16x8*)&Bs[(wn + j * 16 + fr) * 32 + fq * 8];
    __builtin_amdgcn_s_setprio(1);
#pragma unroll
    for (int i = 0; i < 4; ++i)
#pragma unroll
      for (int j = 0; j < 4; ++j)
        acc[i][j] = mfma16(af[i], bfv[j], acc[i][j]);
    __builtin_amdgcn_s_setprio(0);
  }
#pragma unroll
  for (int i = 0; i < 4; ++i)
#pragma unroll
    for (int j = 0; j < 4; ++j)
#pragma unroll
      for (int r = 0; r < 4; ++r) {
        int row = m0 + wm + i * 16 + fq * 4 + r;
        int col = n0 + wn + j * 16 + fr;
        storeC(&C[(size_t)row * N + col], acc[i][j][r]);
      }
}

// ---------------- RMSNorm + RoPE (Q pre-scaled by SM_SCALE) ----------------
__global__ __launch_bounds__(256) void normrope(u16* __restrict__ QKV,
                                                const float* __restrict__ qw,
                                                const float* __restrict__ kw) {
  int wq = threadIdx.x >> 6, lane = threadIdx.x & 63;
  int gid = blockIdx.x * 4 + wq;
  int token = gid / 40, head = gid % 40;
  int pos = token & (SEQ - 1);
  const float* wrow;
  int col;
  float sc;
  if (head < NH) { wrow = qw; col = head * HD; sc = SM_SCALE; }
  else           { wrow = kw; col = DMODEL + (head - NH) * HD; sc = 1.0f; }
  u16* row = QKV + (size_t)token * QKVN + col;
  ushort2 xv = *(const ushort2*)(row + 2 * lane);
  float x1 = bf2f(xv.x), x2 = bf2f(xv.y);
  float ssq = x1 * x1 + x2 * x2;
#pragma unroll
  for (int o = 32; o; o >>= 1) ssq += __shfl_xor(ssq, o, 64);
  float rms = rsqrtf(ssq * (1.0f / HD) + RMS_EPS);
  float y1 = x1 * rms * wrow[2 * lane] * sc;
  float y2 = x2 * rms * wrow[2 * lane + 1] * sc;
  float freq = exp2f((float)lane * -0.20762050593046014f);
  float ang = (float)pos * freq;
  float s, c;
  sincosf(ang, &s, &c);
  ushort2 ov;
  ov.x = f2bf(y1 * c - y2 * s);
  ov.y = f2bf(y1 * s + y2 * c);
  *(ushort2*)(row + 2 * lane) = ov;
}

// ---------------- 4-wave 32x32 swapped-QK^T flash attention ----------------
// Skeleton = r7 proven pipeline (prologue stage, dbuf, {loadV;stageK}->compute->packV->barrier).
// Compute = 32x32 swapped QK^T: mfma32(K,Q) puts P[q=lane&31][kv-slice] lane-local;
// in-register softmax + defer-max(8); P->PV A-frags via packbf + lane^32 shfl.
// LDS 64KB: Ks[2][64][128] (key row&7, pre-swizzled gload_lds src), Vs[2][128][64]
// transposed (key (d^(d>>3))&7 on 16B slots, both write+read).
__global__ __launch_bounds__(256, 2) void attn(const u16* __restrict__ QKV, u16* __restrict__ O) {
  // XCD swizzle: grid 512 = 8 * 64
  int bid0 = blockIdx.x;
  int bid = (bid0 & 7) * 64 + (bid0 >> 3);
  int pairi = bid & 7, h = (bid >> 3) & 31, b = bid >> 8;
  int tid = threadIdx.x, wave = tid >> 6, lane = tid & 63;
  int qn = lane & 31, hi = lane >> 5;
  int hi4 = hi * 4, hi16 = hi * 16;
  int kvh = h >> 2;

  __shared__ __align__(16) u16 Ks[2][64 * 128];
  __shared__ __align__(16) u16 Vs[2][128 * 64];

  size_t tokb = (size_t)b * SEQ;
  const u16* Kg = QKV + tokb * QKVN + DMODEL + kvh * HD;
  const u16* Vg = Kg + NKV * HD;
  int srow = tid >> 4, sl = tid & 15;

  int kk0 = (qn & 7) << 4;  // K-row key; (32+qn)&7 == qn&7
  int d0 = qn, d1 = 32 + qn, d2 = 64 + qn, d3 = 96 + qn;
  int vk0 = ((d0 ^ (d0 >> 3)) & 7) << 4;
  int vk1 = ((d1 ^ (d1 >> 3)) & 7) << 4;
  int vk2 = ((d2 ^ (d2 >> 3)) & 7) << 4;
  int vk3 = ((d3 ^ (d3 >> 3)) & 7) << 4;

  int4 vreg[4];
  auto loadV = [&](int kv0) {
#pragma unroll
    for (int i = 0; i < 4; ++i)
      vreg[i] = *(const int4*)(Vg + (size_t)(kv0 + i * 16 + srow) * QKVN + sl * 8);
  };
  auto stageK = [&](int buf, int kv0) {
#pragma unroll
    for (int i = 0; i < 4; ++i) {
      int row = i * 16 + srow;
      __builtin_amdgcn_global_load_lds(
          (const AS1 u32*)(Kg + (size_t)(kv0 + row) * QKVN + ((sl ^ (row & 7)) * 8)),
          (AS3 u32*)(&Ks[buf][0] + (i * 16 + wave * 4) * 128), 16, 0, 0);
    }
  };
  auto packV = [&](int buf) {
#pragma unroll
    for (int i = 0; i < 4; ++i) {
      int row = i * 16 + srow;
      int4 dvi = vreg[i];
      int4 dpi;
      dpi.x = __shfl_xor(dvi.x, 16, 64);
      dpi.y = __shfl_xor(dvi.y, 16, 64);
      dpi.z = __shfl_xor(dvi.z, 16, 64);
      dpi.w = __shfl_xor(dvi.w, 16, 64);
      if (((tid >> 4) & 1) == 0) {  // even local row writes (kv, kv+1) word pairs
        const u16* own = (const u16*)&dvi;
        const u16* par = (const u16*)&dpi;
#pragma unroll
        for (int j = 0; j < 8; ++j) {
          u32 wv = (u32)own[j] | ((u32)par[j] << 16);
          int d = sl * 8 + j;
          int vk = ((d ^ (d >> 3)) & 7) << 4;
          *(u32*)((char*)&Vs[buf][0] + d * 128 + ((2 * row) ^ vk)) = wv;
        }
      }
    }
  };

  for (int pass = 0; pass < 2; ++pass) {
    int chunk = pass ? (15 - pairi) : pairi;
    int chb = chunk * 128;
    int nt = (chunk + 1) * 2;
    int q0w = chb + wave * 32;
    int qabs = q0w + qn;
    int lim = chunk * 2 + (wave >> 1);
    int diag = q0w & ~63;

    bf16x8 qf[8];
    {
      const u16* qp = QKV + (tokb + q0w + qn) * QKVN + h * HD;
#pragma unroll
      for (int d = 0; d < 8; ++d) qf[d] = *(const bf16x8*)(qp + d * 16 + hi * 8);
    }

    f32x16 o0 = {}, o1 = {}, o2 = {}, o3 = {};
    float mrow = NEG_INF, lsum = 0.f;

    auto tile = [&](int kv0, const u16* Kl, const u16* Vl) {
      f32x16 p0v = {}, p1v = {};
      {
        const char* kb0 = (const char*)Kl + qn * 256;
        const char* kb1 = (const char*)Kl + (32 + qn) * 256;
        __builtin_amdgcn_s_setprio(1);
#pragma unroll
        for (int d = 0; d < 8; ++d) {
          bf16x8 k0 = *(const bf16x8*)(kb0 + ((d * 32 + hi16) ^ kk0));
          bf16x8 k1 = *(const bf16x8*)(kb1 + ((d * 32 + hi16) ^ kk0));
          p0v = mfma32(k0, qf[d], p0v);
          p1v = mfma32(k1, qf[d], p1v);
        }
        __builtin_amdgcn_s_setprio(0);
      }
      if (kv0 == diag) {  // causal mask on diagonal tile
#pragma unroll
        for (int r = 0; r < 16; ++r) {
          int kva = kv0 + (r & 3) + 8 * (r >> 2) + hi4;
          if (kva > qabs) p0v[r] = NEG_INF;
          if (kva + 32 > qabs) p1v[r] = NEG_INF;
        }
      }
      float tmax = NEG_INF;
#pragma unroll
      for (int r = 0; r < 16; ++r) tmax = fmaxf(tmax, fmaxf(p0v[r], p1v[r]));
      tmax = fmaxf(tmax, __shfl_xor(tmax, 32, 64));
      if (!__all(tmax <= mrow + 8.0f)) {  // defer-max rescale
        float nm = fmaxf(mrow, tmax);
        float corr = __expf(mrow - nm);
        mrow = nm;
        lsum *= corr;
#pragma unroll
        for (int r = 0; r < 16; ++r) {
          int srcl = (r & 3) + 8 * (r >> 2) + hi4;
          float cr = __shfl(corr, srcl, 64);
          o0[r] *= cr; o1[r] *= cr; o2[r] *= cr; o3[r] *= cr;
        }
      }
      float rs = 0.f;
#pragma unroll
      for (int r = 0; r < 16; ++r) {
        p0v[r] = __expf(p0v[r] - mrow);
        p1v[r] = __expf(p1v[r] - mrow);
        rs += p0v[r] + p1v[r];
      }
      rs += __shfl_xor(rs, 32, 64);
      lsum += rs;

      auto pv = [&](const f32x16& pk, int kvs) {
#pragma unroll
        for (int e = 0; e < 2; ++e) {
          u32 A = packbf(pk[e * 8 + 0], pk[e * 8 + 1]);
          u32 Bw = packbf(pk[e * 8 + 2], pk[e * 8 + 3]);
          u32 C = packbf(pk[e * 8 + 4], pk[e * 8 + 5]);
          u32 Dw = packbf(pk[e * 8 + 6], pk[e * 8 + 7]);
          u32 sA = __shfl_xor(A, 32, 64), sC = __shfl_xor(C, 32, 64);
          u32 sB = __shfl_xor(Bw, 32, 64), sD = __shfl_xor(Dw, 32, 64);
          union { u32 w[4]; bf16x8 v; } fr;
          fr.w[0] = hi ? sC : A;
          fr.w[1] = hi ? sD : Bw;
          fr.w[2] = hi ? C : sA;
          fr.w[3] = hi ? Dw : sB;
          int off = (kvs * 2 + e) * 32 + hi16;
          __builtin_amdgcn_s_setprio(1);
          o0 = mfma32(fr.v, *(const bf16x8*)((const char*)Vl + d0 * 128 + (off ^ vk0)), o0);
          o1 = mfma32(fr.v, *(const bf16x8*)((const char*)Vl + d1 * 128 + (off ^ vk1)), o1);
          o2 = mfma32(fr.v, *(const bf16x8*)((const char*)Vl + d2 * 128 + (off ^ vk2)), o2);
          o3 = mfma32(fr.v, *(const bf16x8*)((const char*)Vl + d3 * 128 + (off ^ vk3)), o3);
          __builtin_amdgcn_s_setprio(0);
        }
      };
      pv(p0v, 0);
      pv(p1v, 1);
    };

    // prologue: tile 0 into buffer 0 (r7 proven pattern)
    loadV(0);
    stageK(0, 0);
    packV(0);
    __syncthreads();

    for (int t = 0; t < nt; ++t) {
      int cur = t & 1, nxt = cur ^ 1;
      bool more = (t + 1) < nt;
      if (more) {
        loadV((t + 1) * 64);
        stageK(nxt, (t + 1) * 64);
      }
      if (t <= lim) tile(t * 64, &Ks[cur][0], &Vs[cur][0]);
      if (more) packV(nxt);
      __syncthreads();
    }

    // epilogue: normalize + store
#pragma unroll
    for (int r = 0; r < 16; ++r) {
      int ql = (r & 3) + 8 * (r >> 2) + hi4;
      float ls = __shfl(lsum, ql, 64);
      float inv = 1.0f / ls;
      size_t base = (tokb + chb + wave * 32 + ql) * (size_t)DMODEL + h * HD + qn;
      O[base] = f2bf(o0[r] * inv);
      O[base + 32] = f2bf(o1[r] * inv);
      O[base + 64] = f2bf(o2[r] * inv);
      O[base + 96] = f2bf(o3[r] * inv);
    }
  }
}

extern "C" void kernel_launch(void* const* d_in, const int* in_sizes, int n_in,
                              void* d_out, int out_size, void* d_ws, size_t ws_size,
                              hipStream_t stream) {
  const float* x  = (const float*)d_in[0];
  const float* Wq = (const float*)d_in[1];
  const float* Wk = (const float*)d_in[2];
  const float* Wv = (const float*)d_in[3];
  const float* Wo = (const float*)d_in[4];
  const float* qw = (const float*)d_in[5];
  const float* kw = (const float*)d_in[6];
  float* out = (float*)d_out;

  // Workspace (128 MiB), diagnostic layout (AO no longer aliases xb):
  //   [0,   32M)  xb (bf16 x)  -- dead after GEMM1 -> reused as Wot
  //   [32M, 64M)  AO (attn out; region dead after GEMM1, was Wqkvt low half)
  //   [32M, 80M)  Wqkvt        -- dead after GEMM1
  //   [80M, 128M) QKVb
  char* ws = (char*)d_ws;
  u16* xb    = (u16*)(ws);
  u16* Wqkvt = (u16*)(ws + 33554432);
  u16* QKVb  = (u16*)(ws + 83886080);
  u16* Wot   = xb;
  u16* AO    = Wqkvt;

  cvt_f32_bf16<<<2048, 256, 0, stream>>>(x, xb, (2 * SEQ * DMODEL) / 4);
  dim3 tb(32, 8);
  tconv<<<dim3(DMODEL / 32, DMODEL / 32), tb, 0, stream>>>(Wq, Wqkvt, DMODEL, 0);
  tconv<<<dim3((NKV * HD) / 32, DMODEL / 32), tb, 0, stream>>>(Wk, Wqkvt, NKV * HD, DMODEL);
  tconv<<<dim3((NKV * HD) / 32, DMODEL / 32), tb, 0, stream>>>(Wv, Wqkvt, NKV * HD, DMODEL + NKV * HD);

  gemm_bt<u16><<<(4096 / 128) * (QKVN / 128), 256, 0, stream>>>(xb, Wqkvt, QKVb, 4096, QKVN, DMODEL);
  normrope<<<(4096 * 40) / 4, 256, 0, stream>>>(QKVb, qw, kw);

  // Wot into [0,32M) (xb dead); attn writes AO into [32M,64M)
  tconv<<<dim3(DMODEL / 32, DMODEL / 32), tb, 0, stream>>>(Wo, Wot, DMODEL, 0);
  attn<<<512, 256, 0, stream>>>(QKVb, AO);
  gemm_bt<float><<<(4096 / 128) * (DMODEL / 128), 256, 0, stream>>>(AO, Wot, out, 4096, DMODEL, DMODEL);
}